// Round 1
// baseline (236.864 us; speedup 1.0000x reference)
//
#include <hip/hip_runtime.h>
#include <stdint.h>

#define TT 512
#define BB 32
#define EE 512
#define HH 2048

typedef __attribute__((ext_vector_type(8))) short short8;   // 8 x bf16 (4 VGPRs)
typedef __attribute__((ext_vector_type(4))) float f32x4;    // MFMA accumulator

// LDS geometry (in shorts)
#define XROW 528            // 512 data + 16 pad: measured 0 bank conflicts (R1/R3);
                            // 520 gave 8.4M conflicts (R4). Row stride 1056 B = 16*66.
#define XBUF (16 * XROW)    // one 16-t chunk buffer = 8448 shorts (16.5 KB)

static __device__ __forceinline__ unsigned short f2bf(float f) {
    union { float f; unsigned u; } v; v.f = f;
    unsigned u = v.u;
    unsigned r = u + 0x7FFFu + ((u >> 16) & 1u);   // round-to-nearest-even
    return (unsigned short)(r >> 16);
}

static __device__ __forceinline__ float fast_exp(float x) {
    return __builtin_amdgcn_exp2f(x * 1.44269504f);
}
static __device__ __forceinline__ float fast_rcp(float x) {
    return __builtin_amdgcn_rcpf(x);
}

// Async global->LDS DMA, 16 B/lane (wave-uniform LDS base + lane*16).
// Verified correct in R4 (passed, absmax 0.0039).
static __device__ __forceinline__ void load_lds16(const unsigned short* g, unsigned short* l) {
    __builtin_amdgcn_global_load_lds(
        (const __attribute__((address_space(1))) unsigned int*)(uintptr_t)g,
        (__attribute__((address_space(3))) unsigned int*)(uintptr_t)l,
        16, 0, 0);
}

// ---------------------------------------------------------------------------
// Pre-kernel: convert sent (T,B,E) fp32 and W (3H,E) fp32 to bf16 in ws.
// ---------------------------------------------------------------------------
__global__ void convert_inputs(const float* __restrict__ X,
                               const float* __restrict__ W,
                               unsigned short* __restrict__ Xb,
                               unsigned short* __restrict__ Wb) {
    const int nX = TT * BB * EE;              // 8,388,608 (divisible by 8)
    int i = (blockIdx.x * blockDim.x + threadIdx.x) * 8;
    const float* src;
    unsigned short* dst;
    int j;
    if (i < nX) { src = X; dst = Xb; j = i; }
    else        { src = W; dst = Wb; j = i - nX; }
    float4 v0 = *(const float4*)(src + j);
    float4 v1 = *(const float4*)(src + j + 4);
    union { short8 s; unsigned short u[8]; } o;
    o.u[0] = f2bf(v0.x); o.u[1] = f2bf(v0.y); o.u[2] = f2bf(v0.z); o.u[3] = f2bf(v0.w);
    o.u[4] = f2bf(v1.x); o.u[5] = f2bf(v1.y); o.u[6] = f2bf(v1.z); o.u[7] = f2bf(v1.w);
    *(short8*)(dst + j) = o.s;
}

// ---------------------------------------------------------------------------
// Fused QRNN kernel, K-split, rotated software pipeline (this round):
// - Region ch issues MFMA(ch) but runs tail(ch-1) on `prev` accumulators.
//   The tail VALU has NO dependency on the just-issued MFMAs, so the matrix
//   pipe and VALU overlap instead of serializing (m114 two-pipe overlap).
// - exch read for tail(ch-1) is issued EARLY (before the MFMA burst) so its
//   LDS latency hides under MFMA issue. Slot safety: read slot (ch-1)&1 vs
//   publish slot ch&1 differ; overwrite of (ch-1)&1 is publish(ch+1), which
//   sits on the far side of barrier(ch).
// - XCD-aware swizzle: 64 h-group blocks of the SAME batch b cluster on one
//   XCD (id&7 -> xcd, 4 b's per XCD). Their 32 chunk DMAs hit the same
//   512 KB X b-slice -> L2-resident, so the vmcnt(0) drain at each
//   __syncthreads waits ~L2 latency, hidden under the region's compute.
// - Everything else (W pinned in AGPR, A-frag prefetch, DMA staging, one
//   __syncthreads per chunk, hazard set) is the R4/R5-verified structure.
// ---------------------------------------------------------------------------
__launch_bounds__(256, 2)
__global__ void qrnn_fused(const unsigned short* __restrict__ Xb, // bf16 (T,B,E)
                           const unsigned short* __restrict__ Wb, // bf16 (3H,E)
                           const float* __restrict__ bias,        // (3H)
                           float* __restrict__ out)               // (B,H) fp32
{
    __shared__ unsigned short xlds[2 * XBUF];      // 33,792 B
    __shared__ float exch[2][2][64][12];           // 12,288 B  (total 46,080 B)

    const int tid  = threadIdx.x;
    const int wv   = tid >> 6;         // wave 0..3
    const int lane = tid & 63;
    const int q    = lane >> 4;        // quad 0..3
    const int c    = lane & 15;        // column within 16x16 tile
    const int hi   = wv >> 1;          // h-tile 0..1
    const int s    = wv & 1;           // k-half 0..1

    // XCD-aware swizzle: 2048 blocks = 8 XCDs x 4 batches x 64 h-groups.
    // Dispatcher round-robins consecutive ids across XCDs, so ids with the
    // same (id&7) land on one XCD; give each XCD whole b-groups.
    const int id   = blockIdx.x;       // 0..2047
    const int xcd  = id & 7;
    const int slot = id >> 3;          // 0..255 within this XCD
    const int b    = xcd * 4 + (slot >> 6);   // 4 batches per XCD
    const int hgrp = slot & 63;               // 64 h-groups per batch
    const int h    = hgrp * 32 + hi * 16 + c;

    // ---- preload W fragments (this wave's K half); pin into AGPRs ----
    // B-frag layout for 16x16x32: lane holds n = lane&15 (= h), k = q*8 + j.
    short8 wz[8], wf[8], wo[8];
    {
        const unsigned short* wzr = Wb + (size_t)h * EE            + s * 256;
        const unsigned short* wfr = Wb + (size_t)(HH + h) * EE     + s * 256;
        const unsigned short* wor = Wb + (size_t)(2 * HH + h) * EE + s * 256;
#pragma unroll
        for (int k = 0; k < 8; ++k) {
            int e0 = k * 32 + q * 8;
            wz[k] = *(const short8*)(wzr + e0);
            wf[k] = *(const short8*)(wfr + e0);
            wo[k] = *(const short8*)(wor + e0);
        }
    }
    // Liveness pin in AGPR class: loads happen once, stay resident (R3/R4
    // verified: no refetch, no spill).
#pragma unroll
    for (int k = 0; k < 8; ++k) {
        asm volatile("" : "+a"(wz[k]), "+a"(wf[k]), "+a"(wo[k]));
    }

    const float b0 = (s == 0) ? bias[h]          : 0.0f;
    const float b1 = (s == 0) ? bias[HH + h]     : 0.0f;
    const float b2 = (s == 0) ? bias[2 * HH + h] : 0.0f;

    float carry = 0.0f;
    float vmax  = -1e30f;

    // ---- staging: wave wv owns rows wv*4 .. wv*4+3 of each 16-t chunk ----
    const unsigned short* g0 = Xb + ((size_t)(wv * 4) * BB + b) * EE + lane * 8;
    unsigned short* l0 = &xlds[(wv * 4) * XROW];

    auto stage = [&](int n, int slt) {
        const unsigned short* g = g0 + (size_t)n * (16 * BB * EE);
        unsigned short* l = l0 + slt * XBUF;
#pragma unroll
        for (int i = 0; i < 4; ++i)
            load_lds16(g + (size_t)i * (BB * EE), l + i * XROW);
    };

    // tail for one chunk's fully-summed accumulators (s==0 waves only):
    // activations, 16-step affine scan (4 in-lane + cross-quad), carry, max.
    auto do_tail = [&](f32x4 az, f32x4 af, f32x4 ao) {
        float aa[4], mm[4], oo[4];
#pragma unroll
        for (int r = 0; r < 4; ++r) {
            float e2 = fast_exp(2.0f * az[r]);
            float z  = 1.0f - 2.0f * fast_rcp(e2 + 1.0f);  // tanh
            float f  = fast_rcp(1.0f + fast_exp(-af[r]));  // sigmoid
            float o  = fast_rcp(1.0f + fast_exp(-ao[r]));  // sigmoid
            aa[r] = f * z;
            mm[r] = 1.0f - f;
            oo[r] = o;
        }

        // affine scan: compose 4 steps, scan across quads
        float A = aa[0], M = mm[0];
#pragma unroll
        for (int r = 1; r < 4; ++r) { A = aa[r] + mm[r] * A; M = mm[r] * M; }

        float Ap = __shfl_up(A, 16, 64), Mp = __shfl_up(M, 16, 64);
        if (q >= 1) { A = A + M * Ap; M = M * Mp; }
        Ap = __shfl_up(A, 32, 64); Mp = __shfl_up(M, 32, 64);
        if (q >= 2) { A = A + M * Ap; M = M * Mp; }
        float Ae = __shfl_up(A, 16, 64), Me = __shfl_up(M, 16, 64);
        if (q == 0) { Ae = 0.0f; Me = 1.0f; }
        float cc = Ae + Me * carry;

#pragma unroll
        for (int r = 0; r < 4; ++r) {
            cc = aa[r] + mm[r] * cc;
            vmax = fmaxf(vmax, oo[r] * cc);
        }

        float cend = A + M * carry;
        carry = __shfl(cend, 48 + c, 64);
    };

    stage(0, 0);
    __syncthreads();

    f32x4 prevz, prevf, prevo;   // MFMA results of chunk ch-1 (rotation state)

    for (int ch = 0; ch < 32; ++ch) {
        const int buf = ch & 1;
        if (ch < 31) stage(ch + 1, buf ^ 1);

        // ---- prefetch ALL A-frags for this chunk (8 back-to-back b128) ----
        // lane holds m = lane&15 (= t within chunk), k = q*8 + j
        const unsigned short* Abase = &xlds[buf * XBUF + c * XROW + s * 256 + q * 8];
        short8 a[8];
#pragma unroll
        for (int k = 0; k < 8; ++k)
            a[k] = *(const short8*)(Abase + k * 32);

        // ---- early exchange read for tail(ch-1): LDS latency hides under
        //      the MFMA burst below. Slot (ch-1)&1 is stable in this region.
        f32x4 pz, pf, po;
        if (s == 0 && ch > 0) {
            const float* e = &exch[(ch - 1) & 1][hi][lane][0];
            pz = *(const f32x4*)(e);
            pf = *(const f32x4*)(e + 4);
            po = *(const f32x4*)(e + 8);
        }

        // ---- MFMA burst: 24 MFMAs, 3 independent accumulator chains ----
        f32x4 az = {b0, b0, b0, b0};
        f32x4 af = {b1, b1, b1, b1};
        f32x4 ao = {b2, b2, b2, b2};
#pragma unroll
        for (int k = 0; k < 8; ++k) {
            az = __builtin_amdgcn_mfma_f32_16x16x32_bf16(a[k], wz[k], az, 0, 0, 0);
            af = __builtin_amdgcn_mfma_f32_16x16x32_bf16(a[k], wf[k], af, 0, 0, 0);
            ao = __builtin_amdgcn_mfma_f32_16x16x32_bf16(a[k], wo[k], ao, 0, 0, 0);
        }

        // ---- s=1 publishes THIS chunk's partials into its ping-pong slot ----
        if (s == 1) {
            float* e = &exch[ch & 1][hi][lane][0];
            *(f32x4*)(e)     = az;
            *(f32x4*)(e + 4) = af;
            *(f32x4*)(e + 8) = ao;
        }

        // ---- tail(ch-1): pure VALU on prev* + p*; no dependency on the
        //      MFMAs just issued -> overlaps the matrix pipe.
        if (s == 0 && ch > 0) {
            do_tail(prevz + pz, prevf + pf, prevo + po);
        }

        prevz = az; prevf = af; prevo = ao;

        __syncthreads();   // the ONE barrier per chunk: orders publish(ch) vs
                           // read(ch) next region, drains stage(ch+1) DMA,
                           // and fences buf reuse (lgkm+vmcnt drained).
    }

    // ---- epilogue: tail(31) (its exch slot was published in region 31) ----
    if (s == 0) {
        const float* e = &exch[31 & 1][hi][lane][0];
        f32x4 pz = *(const f32x4*)(e);
        f32x4 pf = *(const f32x4*)(e + 4);
        f32x4 po = *(const f32x4*)(e + 8);
        do_tail(prevz + pz, prevf + pf, prevo + po);

        vmax = fmaxf(vmax, __shfl_xor(vmax, 16, 64));
        vmax = fmaxf(vmax, __shfl_xor(vmax, 32, 64));
        if (q == 0) out[(size_t)b * HH + h] = vmax;
    }
}

// ---------------------------------------------------------------------------
extern "C" void kernel_launch(void* const* d_in, const int* in_sizes, int n_in,
                              void* d_out, int out_size, void* d_ws, size_t ws_size,
                              hipStream_t stream) {
    const float* sent = (const float*)d_in[0];
    // d_in[1] = lengths (unused by the math)
    const float* W    = (const float*)d_in[2];
    const float* bias = (const float*)d_in[3];
    float* out        = (float*)d_out;

    const int nX = TT * BB * EE;        // 8,388,608
    const int nW = 3 * HH * EE;         // 3,145,728
    unsigned short* Xb = (unsigned short*)d_ws;
    unsigned short* Wb = Xb + nX;       // 16 MiB offset, 16B-aligned

    int totalVec = (nX + nW) / 8;       // 1,441,792 threads, exact cover
    convert_inputs<<<totalVec / 256, 256, 0, stream>>>(sent, W, Xb, Wb);

    dim3 grid(2048);                    // 1-D: swizzled to (xcd, b, hgrp) in-kernel
    qrnn_fused<<<grid, 256, 0, stream>>>(Xb, Wb, bias, out);
}